// Round 13
// baseline (438.908 us; speedup 1.0000x reference)
//
#include <hip/hip_runtime.h>
#include <hip/hip_bf16.h>
#include <stdint.h>

typedef __hip_bfloat16 bf16;
typedef __attribute__((ext_vector_type(8))) short bf16x8;   // 8 bf16 = 4 VGPRs (MFMA A/B frag)
typedef __attribute__((ext_vector_type(4))) float f32x4;    // 16x16 MFMA C/D frag
typedef __attribute__((ext_vector_type(16))) float f32x16;  // 32x32 MFMA C/D frag
typedef __attribute__((ext_vector_type(4))) unsigned u32x4;

#define B_  2
#define L_  2048
#define D_  1024
#define H_  16
#define HD_ 64
#define BH_ 32
#define L2E 1.4426950408889634f
#define HSZ ((size_t)BH_ * L_ * HD_)

#define DEV static __device__ __forceinline__

DEV short f2bf(float f) {
    bf16 h = __float2bfloat16(f);
    return __builtin_bit_cast(short, h);
}

DEV unsigned pk2(float lo, float hi) {   // bf16(lo) | bf16(hi)<<16
    unsigned a = (unsigned short)__builtin_bit_cast(unsigned short, __float2bfloat16(lo));
    unsigned b = (unsigned short)__builtin_bit_cast(unsigned short, __float2bfloat16(hi));
    return a | (b << 16);
}

DEV f32x4 mfma16(bf16x8 a, bf16x8 b, f32x4 c) {
    return __builtin_amdgcn_mfma_f32_16x16x32_bf16(a, b, c, 0, 0, 0);
}
DEV f32x16 mfma32(bf16x8 a, bf16x8 b, f32x16 c) {
    return __builtin_amdgcn_mfma_f32_32x32x16_bf16(a, b, c, 0, 0, 0);
}

// async global->LDS, 16B per lane; lds ptr must be wave-uniform (HW adds lane*16)
DEV void async_ld16(const void* g, void* lds_uniform) {
    __builtin_amdgcn_global_load_lds((const __attribute__((address_space(1))) void*)g,
                                     (__attribute__((address_space(3))) void*)lds_uniform,
                                     16, 0, 0);
}

// XOR-swizzled element offset inside a [rows][64] bf16 tile (128B rows).
DEV int swz(int row, int col) {
    int blk = (row << 3) + (col >> 3);
    blk ^= (row & 7);
    return (blk << 3) + (col & 7);
}

// ------------------------------------- merged prep: x->bf16 cast + weight cast/transpose
__global__ __launch_bounds__(256) void k_prep(const float* __restrict__ x,
                                              const float* __restrict__ W0, const float* __restrict__ W1,
                                              const float* __restrict__ W2, const float* __restrict__ W3,
                                              bf16* __restrict__ xb, bf16* __restrict__ WT) {
    __shared__ float tile[64][65];
    if (blockIdx.x < 2048) {
        int i = blockIdx.x * 256 + threadIdx.x;
        const float4* src = (const float4*)x + (size_t)i * 2;
        float4 a = src[0], b = src[1];
        bf16x8 v;
        v[0]=f2bf(a.x); v[1]=f2bf(a.y); v[2]=f2bf(a.z); v[3]=f2bf(a.w);
        v[4]=f2bf(b.x); v[5]=f2bf(b.y); v[6]=f2bf(b.z); v[7]=f2bf(b.w);
        *(bf16x8*)(xb + (size_t)i * 8) = v;
        return;
    }
    const int zz = blockIdx.x - 2048;
    const int z = zz >> 8, rem = zz & 255;
    const int by = rem >> 4, bx = rem & 15;
    const float* W = (z == 0) ? W0 : (z == 1) ? W1 : (z == 2) ? W2 : W3;
    const int r0 = by * 64, c0 = bx * 64;
    const int tx = threadIdx.x & 63, ty = threadIdx.x >> 6;
    #pragma unroll
    for (int i = 0; i < 16; ++i) {
        int r = ty + i * 4;
        tile[r][tx] = W[(size_t)(r0 + r) * D_ + c0 + tx];
    }
    __syncthreads();
    bf16* out = WT + (size_t)z * D_ * D_;
    #pragma unroll
    for (int i = 0; i < 16; ++i) {
        int n = ty + i * 4;
        out[(size_t)(c0 + n) * D_ + r0 + tx] = __float2bfloat16(tile[tx][n]);
    }
}

// ---------------------------------------------------------------- GEMM TMx128, BK=64
template <int MODE, int TM>
__global__ __launch_bounds__(256) void k_gemm(const bf16* __restrict__ A, const bf16* __restrict__ BT,
                                              void* __restrict__ C) {
    constexpr int MI = TM / 32;
    __shared__ __align__(16) bf16 As[TM * 64];
    __shared__ __align__(16) bf16 Bs[128 * 64];
    const int t = threadIdx.x;
    const int w = t >> 6, lane = t & 63;
    const int lr = lane & 15, lg = lane >> 4;
    const int wr = (w >> 1) * (TM / 2), wc = (w & 1) * 64;
    const size_t am0 = (size_t)blockIdx.y * TM;
    const size_t bn0 = (size_t)blockIdx.x * 128;

    f32x4 acc[MI][4] = {};

    for (int kt = 0; kt < 1024 / 64; ++kt) {
        const int k0 = kt * 64;
        if (kt) __syncthreads();
        #pragma unroll
        for (int c = 0; c < TM / 32; ++c) {
            int phys = c * 256 + t;
            int lb = phys ^ ((phys >> 3) & 7);
            int row = lb >> 3, cb = lb & 7;
            int ldsoff = (c * 256 + w * 64) * 8;
            async_ld16(A + (am0 + row) * 1024 + k0 + cb * 8, (void*)(As + ldsoff));
        }
        #pragma unroll
        for (int c = 0; c < 4; ++c) {
            int phys = c * 256 + t;
            int lb = phys ^ ((phys >> 3) & 7);
            int row = lb >> 3, cb = lb & 7;
            int ldsoff = (c * 256 + w * 64) * 8;
            async_ld16(BT + (bn0 + row) * 1024 + k0 + cb * 8, (void*)(Bs + ldsoff));
        }
        __syncthreads();
        bf16x8 af[MI][2], bfv[4][2];
        #pragma unroll
        for (int mi = 0; mi < MI; ++mi)
            #pragma unroll
            for (int ks = 0; ks < 2; ++ks)
                af[mi][ks] = *(const bf16x8*)(As + swz(wr + mi * 16 + lr, ks * 32 + lg * 8));
        #pragma unroll
        for (int ni = 0; ni < 4; ++ni)
            #pragma unroll
            for (int ks = 0; ks < 2; ++ks)
                bfv[ni][ks] = *(const bf16x8*)(Bs + swz(wc + ni * 16 + lr, ks * 32 + lg * 8));
        #pragma unroll
        for (int mi = 0; mi < MI; ++mi)
            #pragma unroll
            for (int ni = 0; ni < 4; ++ni) {
                acc[mi][ni] = mfma16(af[mi][0], bfv[ni][0], acc[mi][ni]);
                acc[mi][ni] = mfma16(af[mi][1], bfv[ni][1], acc[mi][ni]);
            }
    }

    #pragma unroll
    for (int mi = 0; mi < MI; ++mi)
        #pragma unroll
        for (int ni = 0; ni < 4; ++ni) {
            const size_t gm0 = am0 + wr + mi * 16 + lg * 4;
            const size_t gn  = bn0 + wc + ni * 16 + lr;
            float v0 = acc[mi][ni][0], v1 = acc[mi][ni][1];
            float v2 = acc[mi][ni][2], v3 = acc[mi][ni][3];
            if (MODE == 1) {
                float* dst = (float*)C + gm0 * 1024 + gn;
                dst[0] = v0; dst[1024] = v1; dst[2048] = v2; dst[3072] = v3;
            } else {
                const int which = (int)(gn >> 10);
                const int hh = (int)((gn >> 6) & 15);
                const int d  = (int)(gn & 63);
                const int bbb = (int)(gm0 >> 11);
                const int ll  = (int)(gm0 & 2047);
                if (which == 2) {
                    bf16* vdst = (bf16*)C + 3 * HSZ + ((size_t)(bbb * H_ + hh) * HD_ + d) * L_ + ll;
                    uint2 pv;
                    pv.x = pk2(v0, v1);
                    pv.y = pk2(v2, v3);
                    *(uint2*)vdst = pv;
                } else {
                    float s = (which == 0) ? 0.18033688011112042f : 1.0f;
                    bf16* dst = (bf16*)C + (size_t)which * HSZ
                              + ((size_t)(bbb * H_ + hh) * L_ + ll) * HD_ + d;
                    dst[0]   = __float2bfloat16(v0 * s);
                    dst[64]  = __float2bfloat16(v1 * s);
                    dst[128] = __float2bfloat16(v2 * s);
                    dst[192] = __float2bfloat16(v3 * s);
                }
            }
        }
}

// ---------------------------------------------------------------- fused attention
// R11 schedule restored (best known): triple-buffer D=3, vmcnt(12), 2 barriers/step.
__global__ __launch_bounds__(256, 2) void k_attn(const bf16* __restrict__ Qb, const bf16* __restrict__ Kb,
                                                 const bf16* __restrict__ VTb, const float* __restrict__ PE,
                                                 bf16* __restrict__ Ob) {
    __shared__ __align__(16) char shm[73728];   // 3 bufs x [K 8KB | V 8KB | PE 8KB]

    const int bid = blockIdx.x;
    const int sw  = (bid & 7) * 64 + (bid >> 3);   // XCD swizzle (bijective, 512 = 8*64)
    const int qt  = sw & 31, h = sw >> 5;
    const int t   = threadIdx.x;
    const int w   = t >> 6, l = t & 63;
    const int qs  = w & 1, b = w >> 1;
    const int q0  = qt * 64 + qs * 32;
    const int lq  = l & 31;
    const int lh  = l >> 5;

    const int pb = (lq >> 2) & 3;
    const int prow = lq + (pb == 1 ? 4 : (pb == 2 ? -4 : 0));

    bf16x8 Qf[4];
    #pragma unroll
    for (int dm = 0; dm < 4; ++dm)
        Qf[dm] = *(const bf16x8*)(Qb + ((size_t)(b * H_ + h) * L_ + q0 + lq) * HD_ + dm * 16 + lh * 8);

    const bf16*  kb    = Kb  + (size_t)(b * H_ + h) * L_ * HD_;
    const bf16*  vbase = VTb + (size_t)h * HD_ * L_;
    const float* peq   = PE  + ((size_t)h * L_ + q0) * L_;

    const int k_srcoff  = (l >> 3) * HD_ + (((l & 7) ^ (l >> 3)) * 8);
    const int vlb = (l & 7) ^ (l >> 3);
    const size_t v_lane = (size_t)(vlb >> 2) * ((size_t)H_ * HD_ * L_)
                        + (size_t)(l >> 3) * L_ + (vlb & 3) * 8;
    const int pe_srcoff = (l >> 3) * L_ + (((l & 7) ^ (l >> 3)) * 4);

    int kro[4];
    #pragma unroll
    for (int dm = 0; dm < 4; ++dm)
        kro[dm] = prow * 64 + (((dm * 2 + lh) ^ (prow & 7)) * 8);
    int vro[2][2];
    #pragma unroll
    for (int d0 = 0; d0 < 2; ++d0)
        #pragma unroll
        for (int m = 0; m < 2; ++m)
            vro[d0][m] = (d0 * 32 + lq) * 64 + (((b * 4 + m * 2 + lh) ^ (lq & 7)) * 8);
    int peo[4];
    #pragma unroll
    for (int g = 0; g < 4; ++g)
        peo[g] = lq * 32 + ((((g >> 1) * 4 + (g & 1) + lh * 2) ^ (lq & 7)) * 4);

#define SH_K(BUF)  (shm + (BUF) * 24576 + b * 4096)
#define SH_V(BUF)  (shm + (BUF) * 24576 + 8192)
#define SH_PE(BUF) (shm + (BUF) * 24576 + 16384 + qs * 4096)

    f32x16 o[2] = {};
    float mrun = -3e38f, lpart = 0.f;

#define STAGE(BUF, TILE) {                                                              \
    const int kv0_ = (TILE) * 32;                                                       \
    _Pragma("unroll") for (int i = 0; i < 2; ++i) {                                     \
        const int c = 2 * qs + i;                                                       \
        async_ld16(kb + (size_t)(kv0_ + c * 8) * HD_ + k_srcoff, (void*)(SH_K(BUF) + c * 1024)); \
    }                                                                                   \
    _Pragma("unroll") for (int i = 0; i < 2; ++i) {                                     \
        const int cv = 2 * w + i;                                                       \
        async_ld16(vbase + v_lane + (size_t)(cv * 8) * L_ + kv0_, (void*)(SH_V(BUF) + cv * 1024)); \
    }                                                                                   \
    _Pragma("unroll") for (int i = 0; i < 2; ++i) {                                     \
        const int c = 2 * b + i;                                                        \
        async_ld16(peq + (size_t)(c * 8) * L_ + kv0_ + pe_srcoff, (void*)(SH_PE(BUF) + c * 1024)); \
    }                                                                                   \
}

#define COMPUTE(BUF) {                                                                  \
    const bf16*  KL = (const bf16*)SH_K(BUF);                                           \
    const bf16*  VL = (const bf16*)SH_V(BUF);                                           \
    const float* PL = (const float*)SH_PE(BUF);                                         \
    bf16x8 kf0_ = *(const bf16x8*)(KL + kro[0]);                                        \
    bf16x8 kf1_ = *(const bf16x8*)(KL + kro[1]);                                        \
    bf16x8 kf2_ = *(const bf16x8*)(KL + kro[2]);                                        \
    bf16x8 kf3_ = *(const bf16x8*)(KL + kro[3]);                                        \
    f32x16 s = {};                                                                      \
    s = mfma32(kf0_, Qf[0], s);                                                         \
    s = mfma32(kf1_, Qf[1], s);                                                         \
    s = mfma32(kf2_, Qf[2], s);                                                         \
    s = mfma32(kf3_, Qf[3], s);                                                         \
    float4 pef_[4];                                                                     \
    _Pragma("unroll") for (int g = 0; g < 4; ++g)                                       \
        pef_[g] = *(const float4*)(PL + peo[g]);                                        \
    float v_[16];                                                                       \
    _Pragma("unroll") for (int r = 0; r < 16; ++r)                                      \
        v_[r] = fmaf(pef_[r >> 2][r & 3], L2E, s[r]);                                   \
    float t0_ = fmaxf(fmaxf(v_[0], v_[1]), fmaxf(v_[2], v_[3]));                        \
    float t1_ = fmaxf(fmaxf(v_[4], v_[5]), fmaxf(v_[6], v_[7]));                        \
    float t2_ = fmaxf(fmaxf(v_[8], v_[9]), fmaxf(v_[10], v_[11]));                      \
    float t3_ = fmaxf(fmaxf(v_[12], v_[13]), fmaxf(v_[14], v_[15]));                    \
    float vmh_ = fmaxf(fmaxf(t0_, t1_), fmaxf(t2_, t3_));                               \
    float vm_ = fmaxf(vmh_, __shfl_xor(vmh_, 32, 64));                                  \
    float mold_ = mrun;                                                                 \
    float mnew_ = mold_;                                                                \
    if (!__all(vm_ <= mold_ + 10.f)) {                                                  \
        mnew_ = fmaxf(mold_, vm_);                                                      \
        float scl_ = __builtin_amdgcn_exp2f(mold_ - mnew_);                             \
        mrun = mnew_;                                                                   \
        lpart *= scl_;                                                                  \
        _Pragma("unroll") for (int r = 0; r < 16; ++r) { o[0][r] *= scl_; o[1][r] *= scl_; } \
    }                                                                                   \
    float p_[16], ssum_ = 0.f;                                                          \
    _Pragma("unroll") for (int r = 0; r < 16; ++r) {                                    \
        p_[r] = __builtin_amdgcn_exp2f(v_[r] - mnew_);                                  \
        ssum_ += p_[r];                                                                 \
    }                                                                                   \
    lpart += ssum_;                                                                     \
    unsigned a_[8];                                                                     \
    _Pragma("unroll") for (int j = 0; j < 8; ++j)                                       \
        a_[j] = pk2(p_[2 * j], p_[2 * j + 1]);                                          \
    u32x4 w0v_ = { a_[0], a_[1], a_[2], a_[3] };                                        \
    u32x4 w1v_ = { a_[4], a_[5], a_[6], a_[7] };                                        \
    bf16x8 pf0_ = __builtin_bit_cast(bf16x8, w0v_);                                     \
    bf16x8 pf1_ = __builtin_bit_cast(bf16x8, w1v_);                                     \
    o[0] = mfma32(*(const bf16x8*)(VL + vro[0][0]), pf0_, o[0]);                        \
    o[0] = mfma32(*(const bf16x8*)(VL + vro[0][1]), pf1_, o[0]);                        \
    o[1] = mfma32(*(const bf16x8*)(VL + vro[1][0]), pf0_, o[1]);                        \
    o[1] = mfma32(*(const bf16x8*)(VL + vro[1][1]), pf1_, o[1]);                        \
}

#define STEP(BUF, PFT) {                                                                \
    asm volatile("s_waitcnt vmcnt(12)" ::: "memory");                                   \
    __builtin_amdgcn_s_barrier();                                                       \
    COMPUTE(BUF)                                                                        \
    __builtin_amdgcn_s_barrier();                                                       \
    STAGE(BUF, PFT)                                                                     \
}

    STAGE(0, 0)
    STAGE(1, 1)
    STAGE(2, 2)

    for (int tp = 0; tp < 21; ++tp) {
        const int e = 3 * tp;
        const int f0 = (e + 3 < 64) ? e + 3 : 63;
        const int f1 = (e + 4 < 64) ? e + 4 : 63;
        const int f2 = (e + 5 < 64) ? e + 5 : 63;
        STEP(0, f0)
        STEP(1, f1)
        STEP(2, f2)
    }
    asm volatile("s_waitcnt vmcnt(12)" ::: "memory");
    __builtin_amdgcn_s_barrier();
    COMPUTE(0)
#undef STEP
#undef COMPUTE
#undef STAGE
#undef SH_K
#undef SH_V
#undef SH_PE

    asm volatile("s_waitcnt vmcnt(0)" ::: "memory");

    float lsum = lpart + __shfl_xor(lpart, 32, 64);
    float inv = __builtin_amdgcn_rcpf(lsum);
    #pragma unroll
    for (int d0 = 0; d0 < 2; ++d0)
        #pragma unroll
        for (int r = 0; r < 16; r += 2) {
            float e0 = o[d0][r] * inv;
            float e1 = o[d0][r + 1] * inv;
            int d = d0 * 32 + ((r & 3) + 8 * (r >> 2)) + lh * 4;
            *(unsigned*)(Ob + ((size_t)b * L_ + q0 + lq) * D_ + h * HD_ + d) = pk2(e0, e1);
        }
}

// ---------------------------------------------------------------- launch
// INSTRUMENTATION ROUND: k_attn launched 4x (idempotent -- same inputs, same Ob).
// attn_duration = (total - ~160) / 3. Deterministic; harness revalidation unaffected.
extern "C" void kernel_launch(void* const* d_in, const int* in_sizes, int n_in,
                              void* d_out, int out_size, void* d_ws, size_t ws_size,
                              hipStream_t stream) {
    const float* x  = (const float*)d_in[0];
    const float* pe = (const float*)d_in[1];
    const float* Wq = (const float*)d_in[2];
    const float* Wk = (const float*)d_in[3];
    const float* Wv = (const float*)d_in[4];
    const float* Wo = (const float*)d_in[5];
    float* out = (float*)d_out;

    const size_t MD = (size_t)4096 * 1024;

    bf16* Xb  = (bf16*)d_ws;        // x in bf16            [4096][1024]
    bf16* WT  = Xb + MD;            // WqT|WkT|WvT|WoT      [4096][1024]
    bf16* Qb  = WT + MD;            // [bh][L][64]  (pre-scaled by 0.125*log2e)
    bf16* Kb  = Qb + HSZ;
    bf16* Vb  = Kb + HSZ;           // (unused slot; V goes straight to VTb)
    bf16* VTb = Vb + HSZ;           // [bh][64][L]  (written by k_gemm<0> transposed)
    bf16* Ob  = VTb + HSZ;          // attention out        [4096][1024]

    k_prep<<<3072, 256, 0, stream>>>(x, Wq, Wk, Wv, Wo, Xb, WT);
    k_gemm<0, 128><<<dim3(24, 32), 256, 0, stream>>>(Xb, WT, (void*)Qb);     // QKV (V -> VTb)
    k_attn<<<512, 256, 0, stream>>>(Qb, Kb, VTb, pe, Ob);
    k_attn<<<512, 256, 0, stream>>>(Qb, Kb, VTb, pe, Ob);   // timing probe x3
    k_attn<<<512, 256, 0, stream>>>(Qb, Kb, VTb, pe, Ob);
    k_attn<<<512, 256, 0, stream>>>(Qb, Kb, VTb, pe, Ob);
    k_gemm<1, 64><<<dim3(8, 64), 256, 0, stream>>>(Ob, WT + (size_t)3072 * 1024, (void*)out);
}

// Round 14
// 166.886 us; speedup vs baseline: 2.6300x; 2.6300x over previous
//
#include <hip/hip_runtime.h>
#include <hip/hip_bf16.h>
#include <stdint.h>

typedef __hip_bfloat16 bf16;
typedef __attribute__((ext_vector_type(8))) short bf16x8;   // 8 bf16 = 4 VGPRs (MFMA A/B frag)
typedef __attribute__((ext_vector_type(4))) float f32x4;    // 16x16 MFMA C/D frag
typedef __attribute__((ext_vector_type(16))) float f32x16;  // 32x32 MFMA C/D frag
typedef __attribute__((ext_vector_type(4))) unsigned u32x4;

#define B_  2
#define L_  2048
#define D_  1024
#define H_  16
#define HD_ 64
#define BH_ 32
#define L2E 1.4426950408889634f
#define HSZ ((size_t)BH_ * L_ * HD_)

#define DEV static __device__ __forceinline__

DEV short f2bf(float f) {
    bf16 h = __float2bfloat16(f);
    return __builtin_bit_cast(short, h);
}

DEV unsigned pk2(float lo, float hi) {   // bf16(lo) | bf16(hi)<<16
    unsigned a = (unsigned short)__builtin_bit_cast(unsigned short, __float2bfloat16(lo));
    unsigned b = (unsigned short)__builtin_bit_cast(unsigned short, __float2bfloat16(hi));
    return a | (b << 16);
}

DEV f32x4 mfma16(bf16x8 a, bf16x8 b, f32x4 c) {
    return __builtin_amdgcn_mfma_f32_16x16x32_bf16(a, b, c, 0, 0, 0);
}
DEV f32x16 mfma32(bf16x8 a, bf16x8 b, f32x16 c) {
    return __builtin_amdgcn_mfma_f32_32x32x16_bf16(a, b, c, 0, 0, 0);
}

// async global->LDS, 16B per lane; lds ptr must be wave-uniform (HW adds lane*16)
DEV void async_ld16(const void* g, void* lds_uniform) {
    __builtin_amdgcn_global_load_lds((const __attribute__((address_space(1))) void*)g,
                                     (__attribute__((address_space(3))) void*)lds_uniform,
                                     16, 0, 0);
}

// XOR-swizzled element offset inside a [rows][64] bf16 tile (128B rows).
DEV int swz(int row, int col) {
    int blk = (row << 3) + (col >> 3);
    blk ^= (row & 7);
    return (blk << 3) + (col & 7);
}

// ------------------------------------- merged prep: x->bf16 cast + weight cast/transpose
__global__ __launch_bounds__(256) void k_prep(const float* __restrict__ x,
                                              const float* __restrict__ W0, const float* __restrict__ W1,
                                              const float* __restrict__ W2, const float* __restrict__ W3,
                                              bf16* __restrict__ xb, bf16* __restrict__ WT) {
    __shared__ float tile[64][65];
    if (blockIdx.x < 2048) {
        int i = blockIdx.x * 256 + threadIdx.x;
        const float4* src = (const float4*)x + (size_t)i * 2;
        float4 a = src[0], b = src[1];
        bf16x8 v;
        v[0]=f2bf(a.x); v[1]=f2bf(a.y); v[2]=f2bf(a.z); v[3]=f2bf(a.w);
        v[4]=f2bf(b.x); v[5]=f2bf(b.y); v[6]=f2bf(b.z); v[7]=f2bf(b.w);
        *(bf16x8*)(xb + (size_t)i * 8) = v;
        return;
    }
    const int zz = blockIdx.x - 2048;
    const int z = zz >> 8, rem = zz & 255;
    const int by = rem >> 4, bx = rem & 15;
    const float* W = (z == 0) ? W0 : (z == 1) ? W1 : (z == 2) ? W2 : W3;
    const int r0 = by * 64, c0 = bx * 64;
    const int tx = threadIdx.x & 63, ty = threadIdx.x >> 6;
    #pragma unroll
    for (int i = 0; i < 16; ++i) {
        int r = ty + i * 4;
        tile[r][tx] = W[(size_t)(r0 + r) * D_ + c0 + tx];
    }
    __syncthreads();
    bf16* out = WT + (size_t)z * D_ * D_;
    #pragma unroll
    for (int i = 0; i < 16; ++i) {
        int n = ty + i * 4;
        out[(size_t)(c0 + n) * D_ + r0 + tx] = __float2bfloat16(tile[tx][n]);
    }
}

// ---------------------------------------------------------------- GEMM TMx128, BK=64
// XCD-swizzled block order (bijective: grid%8==0 for both instantiations).
template <int MODE, int TM>
__global__ __launch_bounds__(256) void k_gemm(const bf16* __restrict__ A, const bf16* __restrict__ BT,
                                              void* __restrict__ C) {
    constexpr int MI = TM / 32;
    __shared__ __align__(16) bf16 As[TM * 64];
    __shared__ __align__(16) bf16 Bs[128 * 64];
    const int t = threadIdx.x;
    const int w = t >> 6, lane = t & 63;
    const int lr = lane & 15, lg = lane >> 4;
    const int wr = (w >> 1) * (TM / 2), wc = (w & 1) * 64;

    // XCD swizzle: consecutive 1/8 of the grid per XCD
    const int lin = blockIdx.y * gridDim.x + blockIdx.x;
    const int cpx = (gridDim.x * gridDim.y) >> 3;
    const int sl  = (lin & 7) * cpx + (lin >> 3);
    const int bx  = sl % gridDim.x, by = sl / gridDim.x;

    const size_t am0 = (size_t)by * TM;
    const size_t bn0 = (size_t)bx * 128;

    f32x4 acc[MI][4] = {};

    for (int kt = 0; kt < 1024 / 64; ++kt) {
        const int k0 = kt * 64;
        if (kt) __syncthreads();
        #pragma unroll
        for (int c = 0; c < TM / 32; ++c) {
            int phys = c * 256 + t;
            int lb = phys ^ ((phys >> 3) & 7);
            int row = lb >> 3, cb = lb & 7;
            int ldsoff = (c * 256 + w * 64) * 8;
            async_ld16(A + (am0 + row) * 1024 + k0 + cb * 8, (void*)(As + ldsoff));
        }
        #pragma unroll
        for (int c = 0; c < 4; ++c) {
            int phys = c * 256 + t;
            int lb = phys ^ ((phys >> 3) & 7);
            int row = lb >> 3, cb = lb & 7;
            int ldsoff = (c * 256 + w * 64) * 8;
            async_ld16(BT + (bn0 + row) * 1024 + k0 + cb * 8, (void*)(Bs + ldsoff));
        }
        __syncthreads();
        bf16x8 af[MI][2], bfv[4][2];
        #pragma unroll
        for (int mi = 0; mi < MI; ++mi)
            #pragma unroll
            for (int ks = 0; ks < 2; ++ks)
                af[mi][ks] = *(const bf16x8*)(As + swz(wr + mi * 16 + lr, ks * 32 + lg * 8));
        #pragma unroll
        for (int ni = 0; ni < 4; ++ni)
            #pragma unroll
            for (int ks = 0; ks < 2; ++ks)
                bfv[ni][ks] = *(const bf16x8*)(Bs + swz(wc + ni * 16 + lr, ks * 32 + lg * 8));
        __builtin_amdgcn_s_setprio(1);
        #pragma unroll
        for (int mi = 0; mi < MI; ++mi)
            #pragma unroll
            for (int ni = 0; ni < 4; ++ni) {
                acc[mi][ni] = mfma16(af[mi][0], bfv[ni][0], acc[mi][ni]);
                acc[mi][ni] = mfma16(af[mi][1], bfv[ni][1], acc[mi][ni]);
            }
        __builtin_amdgcn_s_setprio(0);
    }

    #pragma unroll
    for (int mi = 0; mi < MI; ++mi)
        #pragma unroll
        for (int ni = 0; ni < 4; ++ni) {
            const size_t gm0 = am0 + wr + mi * 16 + lg * 4;
            const size_t gn  = bn0 + wc + ni * 16 + lr;
            float v0 = acc[mi][ni][0], v1 = acc[mi][ni][1];
            float v2 = acc[mi][ni][2], v3 = acc[mi][ni][3];
            if (MODE == 1) {
                float* dst = (float*)C + gm0 * 1024 + gn;
                dst[0] = v0; dst[1024] = v1; dst[2048] = v2; dst[3072] = v3;
            } else {
                const int which = (int)(gn >> 10);
                const int hh = (int)((gn >> 6) & 15);
                const int d  = (int)(gn & 63);
                const int bbb = (int)(gm0 >> 11);
                const int ll  = (int)(gm0 & 2047);
                if (which == 2) {
                    bf16* vdst = (bf16*)C + 3 * HSZ + ((size_t)(bbb * H_ + hh) * HD_ + d) * L_ + ll;
                    uint2 pv;
                    pv.x = pk2(v0, v1);
                    pv.y = pk2(v2, v3);
                    *(uint2*)vdst = pv;
                } else {
                    float s = (which == 0) ? 0.18033688011112042f : 1.0f;
                    bf16* dst = (bf16*)C + (size_t)which * HSZ
                              + ((size_t)(bbb * H_ + hh) * L_ + ll) * HD_ + d;
                    dst[0]   = __float2bfloat16(v0 * s);
                    dst[64]  = __float2bfloat16(v1 * s);
                    dst[128] = __float2bfloat16(v2 * s);
                    dst[192] = __float2bfloat16(v3 * s);
                }
            }
        }
}

// ---------------------------------------------------------------- fused attention
// R11 schedule (best known): triple-buffer D=3, vmcnt(12), 2 barriers/step.
// R14: s_setprio(1) wrapped around both MFMA clusters (T5).
__global__ __launch_bounds__(256, 2) void k_attn(const bf16* __restrict__ Qb, const bf16* __restrict__ Kb,
                                                 const bf16* __restrict__ VTb, const float* __restrict__ PE,
                                                 bf16* __restrict__ Ob) {
    __shared__ __align__(16) char shm[73728];   // 3 bufs x [K 8KB | V 8KB | PE 8KB]

    const int bid = blockIdx.x;
    const int sw  = (bid & 7) * 64 + (bid >> 3);   // XCD swizzle (bijective, 512 = 8*64)
    const int qt  = sw & 31, h = sw >> 5;
    const int t   = threadIdx.x;
    const int w   = t >> 6, l = t & 63;
    const int qs  = w & 1, b = w >> 1;
    const int q0  = qt * 64 + qs * 32;
    const int lq  = l & 31;
    const int lh  = l >> 5;

    const int pb = (lq >> 2) & 3;
    const int prow = lq + (pb == 1 ? 4 : (pb == 2 ? -4 : 0));

    bf16x8 Qf[4];
    #pragma unroll
    for (int dm = 0; dm < 4; ++dm)
        Qf[dm] = *(const bf16x8*)(Qb + ((size_t)(b * H_ + h) * L_ + q0 + lq) * HD_ + dm * 16 + lh * 8);

    const bf16*  kb    = Kb  + (size_t)(b * H_ + h) * L_ * HD_;
    const bf16*  vbase = VTb + (size_t)h * HD_ * L_;
    const float* peq   = PE  + ((size_t)h * L_ + q0) * L_;

    const int k_srcoff  = (l >> 3) * HD_ + (((l & 7) ^ (l >> 3)) * 8);
    const int vlb = (l & 7) ^ (l >> 3);
    const size_t v_lane = (size_t)(vlb >> 2) * ((size_t)H_ * HD_ * L_)
                        + (size_t)(l >> 3) * L_ + (vlb & 3) * 8;
    const int pe_srcoff = (l >> 3) * L_ + (((l & 7) ^ (l >> 3)) * 4);

    int kro[4];
    #pragma unroll
    for (int dm = 0; dm < 4; ++dm)
        kro[dm] = prow * 64 + (((dm * 2 + lh) ^ (prow & 7)) * 8);
    int vro[2][2];
    #pragma unroll
    for (int d0 = 0; d0 < 2; ++d0)
        #pragma unroll
        for (int m = 0; m < 2; ++m)
            vro[d0][m] = (d0 * 32 + lq) * 64 + (((b * 4 + m * 2 + lh) ^ (lq & 7)) * 8);
    int peo[4];
    #pragma unroll
    for (int g = 0; g < 4; ++g)
        peo[g] = lq * 32 + ((((g >> 1) * 4 + (g & 1) + lh * 2) ^ (lq & 7)) * 4);

#define SH_K(BUF)  (shm + (BUF) * 24576 + b * 4096)
#define SH_V(BUF)  (shm + (BUF) * 24576 + 8192)
#define SH_PE(BUF) (shm + (BUF) * 24576 + 16384 + qs * 4096)

    f32x16 o[2] = {};
    float mrun = -3e38f, lpart = 0.f;

#define STAGE(BUF, TILE) {                                                              \
    const int kv0_ = (TILE) * 32;                                                       \
    _Pragma("unroll") for (int i = 0; i < 2; ++i) {                                     \
        const int c = 2 * qs + i;                                                       \
        async_ld16(kb + (size_t)(kv0_ + c * 8) * HD_ + k_srcoff, (void*)(SH_K(BUF) + c * 1024)); \
    }                                                                                   \
    _Pragma("unroll") for (int i = 0; i < 2; ++i) {                                     \
        const int cv = 2 * w + i;                                                       \
        async_ld16(vbase + v_lane + (size_t)(cv * 8) * L_ + kv0_, (void*)(SH_V(BUF) + cv * 1024)); \
    }                                                                                   \
    _Pragma("unroll") for (int i = 0; i < 2; ++i) {                                     \
        const int c = 2 * b + i;                                                        \
        async_ld16(peq + (size_t)(c * 8) * L_ + kv0_ + pe_srcoff, (void*)(SH_PE(BUF) + c * 1024)); \
    }                                                                                   \
}

#define COMPUTE(BUF) {                                                                  \
    const bf16*  KL = (const bf16*)SH_K(BUF);                                           \
    const bf16*  VL = (const bf16*)SH_V(BUF);                                           \
    const float* PL = (const float*)SH_PE(BUF);                                         \
    bf16x8 kf0_ = *(const bf16x8*)(KL + kro[0]);                                        \
    bf16x8 kf1_ = *(const bf16x8*)(KL + kro[1]);                                        \
    bf16x8 kf2_ = *(const bf16x8*)(KL + kro[2]);                                        \
    bf16x8 kf3_ = *(const bf16x8*)(KL + kro[3]);                                        \
    f32x16 s = {};                                                                      \
    __builtin_amdgcn_s_setprio(1);                                                      \
    s = mfma32(kf0_, Qf[0], s);                                                         \
    s = mfma32(kf1_, Qf[1], s);                                                         \
    s = mfma32(kf2_, Qf[2], s);                                                         \
    s = mfma32(kf3_, Qf[3], s);                                                         \
    __builtin_amdgcn_s_setprio(0);                                                      \
    float4 pef_[4];                                                                     \
    _Pragma("unroll") for (int g = 0; g < 4; ++g)                                       \
        pef_[g] = *(const float4*)(PL + peo[g]);                                        \
    float v_[16];                                                                       \
    _Pragma("unroll") for (int r = 0; r < 16; ++r)                                      \
        v_[r] = fmaf(pef_[r >> 2][r & 3], L2E, s[r]);                                   \
    float t0_ = fmaxf(fmaxf(v_[0], v_[1]), fmaxf(v_[2], v_[3]));                        \
    float t1_ = fmaxf(fmaxf(v_[4], v_[5]), fmaxf(v_[6], v_[7]));                        \
    float t2_ = fmaxf(fmaxf(v_[8], v_[9]), fmaxf(v_[10], v_[11]));                      \
    float t3_ = fmaxf(fmaxf(v_[12], v_[13]), fmaxf(v_[14], v_[15]));                    \
    float vmh_ = fmaxf(fmaxf(t0_, t1_), fmaxf(t2_, t3_));                               \
    float vm_ = fmaxf(vmh_, __shfl_xor(vmh_, 32, 64));                                  \
    float mold_ = mrun;                                                                 \
    float mnew_ = mold_;                                                                \
    if (!__all(vm_ <= mold_ + 10.f)) {                                                  \
        mnew_ = fmaxf(mold_, vm_);                                                      \
        float scl_ = __builtin_amdgcn_exp2f(mold_ - mnew_);                             \
        mrun = mnew_;                                                                   \
        lpart *= scl_;                                                                  \
        _Pragma("unroll") for (int r = 0; r < 16; ++r) { o[0][r] *= scl_; o[1][r] *= scl_; } \
    }                                                                                   \
    float p_[16], ssum_ = 0.f;                                                          \
    _Pragma("unroll") for (int r = 0; r < 16; ++r) {                                    \
        p_[r] = __builtin_amdgcn_exp2f(v_[r] - mnew_);                                  \
        ssum_ += p_[r];                                                                 \
    }                                                                                   \
    lpart += ssum_;                                                                     \
    unsigned a_[8];                                                                     \
    _Pragma("unroll") for (int j = 0; j < 8; ++j)                                       \
        a_[j] = pk2(p_[2 * j], p_[2 * j + 1]);                                          \
    u32x4 w0v_ = { a_[0], a_[1], a_[2], a_[3] };                                        \
    u32x4 w1v_ = { a_[4], a_[5], a_[6], a_[7] };                                        \
    bf16x8 pf0_ = __builtin_bit_cast(bf16x8, w0v_);                                     \
    bf16x8 pf1_ = __builtin_bit_cast(bf16x8, w1v_);                                     \
    __builtin_amdgcn_s_setprio(1);                                                      \
    o[0] = mfma32(*(const bf16x8*)(VL + vro[0][0]), pf0_, o[0]);                        \
    o[0] = mfma32(*(const bf16x8*)(VL + vro[0][1]), pf1_, o[0]);                        \
    o[1] = mfma32(*(const bf16x8*)(VL + vro[1][0]), pf0_, o[1]);                        \
    o[1] = mfma32(*(const bf16x8*)(VL + vro[1][1]), pf1_, o[1]);                        \
    __builtin_amdgcn_s_setprio(0);                                                      \
}

#define STEP(BUF, PFT) {                                                                \
    asm volatile("s_waitcnt vmcnt(12)" ::: "memory");                                   \
    __builtin_amdgcn_s_barrier();                                                       \
    COMPUTE(BUF)                                                                        \
    __builtin_amdgcn_s_barrier();                                                       \
    STAGE(BUF, PFT)                                                                     \
}

    STAGE(0, 0)
    STAGE(1, 1)
    STAGE(2, 2)

    for (int tp = 0; tp < 21; ++tp) {
        const int e = 3 * tp;
        const int f0 = (e + 3 < 64) ? e + 3 : 63;
        const int f1 = (e + 4 < 64) ? e + 4 : 63;
        const int f2 = (e + 5 < 64) ? e + 5 : 63;
        STEP(0, f0)
        STEP(1, f1)
        STEP(2, f2)
    }
    asm volatile("s_waitcnt vmcnt(12)" ::: "memory");
    __builtin_amdgcn_s_barrier();
    COMPUTE(0)
#undef STEP
#undef COMPUTE
#undef STAGE
#undef SH_K
#undef SH_V
#undef SH_PE

    asm volatile("s_waitcnt vmcnt(0)" ::: "memory");

    float lsum = lpart + __shfl_xor(lpart, 32, 64);
    float inv = __builtin_amdgcn_rcpf(lsum);
    #pragma unroll
    for (int d0 = 0; d0 < 2; ++d0)
        #pragma unroll
        for (int r = 0; r < 16; r += 2) {
            float e0 = o[d0][r] * inv;
            float e1 = o[d0][r + 1] * inv;
            int d = d0 * 32 + ((r & 3) + 8 * (r >> 2)) + lh * 4;
            *(unsigned*)(Ob + ((size_t)b * L_ + q0 + lq) * D_ + h * HD_ + d) = pk2(e0, e1);
        }
}

// ---------------------------------------------------------------- launch
extern "C" void kernel_launch(void* const* d_in, const int* in_sizes, int n_in,
                              void* d_out, int out_size, void* d_ws, size_t ws_size,
                              hipStream_t stream) {
    const float* x  = (const float*)d_in[0];
    const float* pe = (const float*)d_in[1];
    const float* Wq = (const float*)d_in[2];
    const float* Wk = (const float*)d_in[3];
    const float* Wv = (const float*)d_in[4];
    const float* Wo = (const float*)d_in[5];
    float* out = (float*)d_out;

    const size_t MD = (size_t)4096 * 1024;

    bf16* Xb  = (bf16*)d_ws;        // x in bf16            [4096][1024]
    bf16* WT  = Xb + MD;            // WqT|WkT|WvT|WoT      [4096][1024]
    bf16* Qb  = WT + MD;            // [bh][L][64]  (pre-scaled by 0.125*log2e)
    bf16* Kb  = Qb + HSZ;
    bf16* Vb  = Kb + HSZ;           // (unused slot; V goes straight to VTb)
    bf16* VTb = Vb + HSZ;           // [bh][64][L]  (written by k_gemm<0> transposed)
    bf16* Ob  = VTb + HSZ;          // attention out        [4096][1024]

    k_prep<<<3072, 256, 0, stream>>>(x, Wq, Wk, Wv, Wo, Xb, WT);
    k_gemm<0, 128><<<dim3(24, 32), 256, 0, stream>>>(Xb, WT, (void*)Qb);     // QKV (V -> VTb)
    k_attn<<<512, 256, 0, stream>>>(Qb, Kb, VTb, pe, Ob);
    k_gemm<1, 64><<<dim3(8, 64), 256, 0, stream>>>(Ob, WT + (size_t)3072 * 1024, (void*)out);
}

// Round 15
// 159.536 us; speedup vs baseline: 2.7512x; 1.0461x over previous
//
#include <hip/hip_runtime.h>
#include <hip/hip_bf16.h>
#include <stdint.h>

typedef __hip_bfloat16 bf16;
typedef __attribute__((ext_vector_type(8))) short bf16x8;   // 8 bf16 = 4 VGPRs (MFMA A/B frag)
typedef __attribute__((ext_vector_type(4))) float f32x4;    // 16x16 MFMA C/D frag
typedef __attribute__((ext_vector_type(16))) float f32x16;  // 32x32 MFMA C/D frag
typedef __attribute__((ext_vector_type(4))) unsigned u32x4;

#define B_  2
#define L_  2048
#define D_  1024
#define H_  16
#define HD_ 64
#define BH_ 32
#define L2E 1.4426950408889634f
#define HSZ ((size_t)BH_ * L_ * HD_)

#define DEV static __device__ __forceinline__

DEV short f2bf(float f) {
    bf16 h = __float2bfloat16(f);
    return __builtin_bit_cast(short, h);
}

DEV unsigned pk2(float lo, float hi) {   // bf16(lo) | bf16(hi)<<16
    unsigned a = (unsigned short)__builtin_bit_cast(unsigned short, __float2bfloat16(lo));
    unsigned b = (unsigned short)__builtin_bit_cast(unsigned short, __float2bfloat16(hi));
    return a | (b << 16);
}

DEV f32x4 mfma16(bf16x8 a, bf16x8 b, f32x4 c) {
    return __builtin_amdgcn_mfma_f32_16x16x32_bf16(a, b, c, 0, 0, 0);
}
DEV f32x16 mfma32(bf16x8 a, bf16x8 b, f32x16 c) {
    return __builtin_amdgcn_mfma_f32_32x32x16_bf16(a, b, c, 0, 0, 0);
}

// async global->LDS, 16B per lane; lds ptr must be wave-uniform (HW adds lane*16)
DEV void async_ld16(const void* g, void* lds_uniform) {
    __builtin_amdgcn_global_load_lds((const __attribute__((address_space(1))) void*)g,
                                     (__attribute__((address_space(3))) void*)lds_uniform,
                                     16, 0, 0);
}

// XOR-swizzled element offset inside a [rows][64] bf16 tile (128B rows).
DEV int swz(int row, int col) {
    int blk = (row << 3) + (col >> 3);
    blk ^= (row & 7);
    return (blk << 3) + (col & 7);
}

// ------------------------------------- merged prep: x->bf16 cast + weight cast/transpose
__global__ __launch_bounds__(256) void k_prep(const float* __restrict__ x,
                                              const float* __restrict__ W0, const float* __restrict__ W1,
                                              const float* __restrict__ W2, const float* __restrict__ W3,
                                              bf16* __restrict__ xb, bf16* __restrict__ WT) {
    __shared__ float tile[64][65];
    if (blockIdx.x < 2048) {
        int i = blockIdx.x * 256 + threadIdx.x;
        const float4* src = (const float4*)x + (size_t)i * 2;
        float4 a = src[0], b = src[1];
        bf16x8 v;
        v[0]=f2bf(a.x); v[1]=f2bf(a.y); v[2]=f2bf(a.z); v[3]=f2bf(a.w);
        v[4]=f2bf(b.x); v[5]=f2bf(b.y); v[6]=f2bf(b.z); v[7]=f2bf(b.w);
        *(bf16x8*)(xb + (size_t)i * 8) = v;
        return;
    }
    const int zz = blockIdx.x - 2048;
    const int z = zz >> 8, rem = zz & 255;
    const int by = rem >> 4, bx = rem & 15;
    const float* W = (z == 0) ? W0 : (z == 1) ? W1 : (z == 2) ? W2 : W3;
    const int r0 = by * 64, c0 = bx * 64;
    const int tx = threadIdx.x & 63, ty = threadIdx.x >> 6;
    #pragma unroll
    for (int i = 0; i < 16; ++i) {
        int r = ty + i * 4;
        tile[r][tx] = W[(size_t)(r0 + r) * D_ + c0 + tx];
    }
    __syncthreads();
    bf16* out = WT + (size_t)z * D_ * D_;
    #pragma unroll
    for (int i = 0; i < 16; ++i) {
        int n = ty + i * 4;
        out[(size_t)(c0 + n) * D_ + r0 + tx] = __float2bfloat16(tile[tx][n]);
    }
}

// ---------------------------------------------------------------- GEMM TMx128, BK=64
template <int MODE, int TM>
__global__ __launch_bounds__(256) void k_gemm(const bf16* __restrict__ A, const bf16* __restrict__ BT,
                                              void* __restrict__ C) {
    constexpr int MI = TM / 32;
    __shared__ __align__(16) bf16 As[TM * 64];
    __shared__ __align__(16) bf16 Bs[128 * 64];
    const int t = threadIdx.x;
    const int w = t >> 6, lane = t & 63;
    const int lr = lane & 15, lg = lane >> 4;
    const int wr = (w >> 1) * (TM / 2), wc = (w & 1) * 64;
    const size_t am0 = (size_t)blockIdx.y * TM;
    const size_t bn0 = (size_t)blockIdx.x * 128;

    f32x4 acc[MI][4] = {};

    for (int kt = 0; kt < 1024 / 64; ++kt) {
        const int k0 = kt * 64;
        if (kt) __syncthreads();
        #pragma unroll
        for (int c = 0; c < TM / 32; ++c) {
            int phys = c * 256 + t;
            int lb = phys ^ ((phys >> 3) & 7);
            int row = lb >> 3, cb = lb & 7;
            int ldsoff = (c * 256 + w * 64) * 8;
            async_ld16(A + (am0 + row) * 1024 + k0 + cb * 8, (void*)(As + ldsoff));
        }
        #pragma unroll
        for (int c = 0; c < 4; ++c) {
            int phys = c * 256 + t;
            int lb = phys ^ ((phys >> 3) & 7);
            int row = lb >> 3, cb = lb & 7;
            int ldsoff = (c * 256 + w * 64) * 8;
            async_ld16(BT + (bn0 + row) * 1024 + k0 + cb * 8, (void*)(Bs + ldsoff));
        }
        __syncthreads();
        bf16x8 af[MI][2], bfv[4][2];
        #pragma unroll
        for (int mi = 0; mi < MI; ++mi)
            #pragma unroll
            for (int ks = 0; ks < 2; ++ks)
                af[mi][ks] = *(const bf16x8*)(As + swz(wr + mi * 16 + lr, ks * 32 + lg * 8));
        #pragma unroll
        for (int ni = 0; ni < 4; ++ni)
            #pragma unroll
            for (int ks = 0; ks < 2; ++ks)
                bfv[ni][ks] = *(const bf16x8*)(Bs + swz(wc + ni * 16 + lr, ks * 32 + lg * 8));
        #pragma unroll
        for (int mi = 0; mi < MI; ++mi)
            #pragma unroll
            for (int ni = 0; ni < 4; ++ni) {
                acc[mi][ni] = mfma16(af[mi][0], bfv[ni][0], acc[mi][ni]);
                acc[mi][ni] = mfma16(af[mi][1], bfv[ni][1], acc[mi][ni]);
            }
    }

    #pragma unroll
    for (int mi = 0; mi < MI; ++mi)
        #pragma unroll
        for (int ni = 0; ni < 4; ++ni) {
            const size_t gm0 = am0 + wr + mi * 16 + lg * 4;
            const size_t gn  = bn0 + wc + ni * 16 + lr;
            float v0 = acc[mi][ni][0], v1 = acc[mi][ni][1];
            float v2 = acc[mi][ni][2], v3 = acc[mi][ni][3];
            if (MODE == 1) {
                float* dst = (float*)C + gm0 * 1024 + gn;
                dst[0] = v0; dst[1024] = v1; dst[2048] = v2; dst[3072] = v3;
            } else {
                const int which = (int)(gn >> 10);
                const int hh = (int)((gn >> 6) & 15);
                const int d  = (int)(gn & 63);
                const int bbb = (int)(gm0 >> 11);
                const int ll  = (int)(gm0 & 2047);
                if (which == 2) {
                    bf16* vdst = (bf16*)C + 3 * HSZ + ((size_t)(bbb * H_ + hh) * HD_ + d) * L_ + ll;
                    uint2 pv;
                    pv.x = pk2(v0, v1);
                    pv.y = pk2(v2, v3);
                    *(uint2*)vdst = pv;
                } else {
                    float s = (which == 0) ? 0.18033688011112042f : 1.0f;
                    bf16* dst = (bf16*)C + (size_t)which * HSZ
                              + ((size_t)(bbb * H_ + hh) * L_ + ll) * HD_ + d;
                    dst[0]   = __float2bfloat16(v0 * s);
                    dst[64]  = __float2bfloat16(v1 * s);
                    dst[128] = __float2bfloat16(v2 * s);
                    dst[192] = __float2bfloat16(v3 * s);
                }
            }
        }
}

// ---------------------------------------------------------------- fused attention
// R15: 2 tiles per barrier-pair. Triple buffer (tile t -> buf t%3), 12 DMA/iter,
// vmcnt(6) -> tiles 2i,2i+1 landed. Stage targets after barrier-2 are exactly the
// two just-computed buffers (race-free as R11). Barriers 130 -> 64; tile-B QK^T
// overlaps tile-A softmax (MFMA || VALU).
__global__ __launch_bounds__(256, 2) void k_attn(const bf16* __restrict__ Qb, const bf16* __restrict__ Kb,
                                                 const bf16* __restrict__ VTb, const float* __restrict__ PE,
                                                 bf16* __restrict__ Ob) {
    __shared__ __align__(16) char shm[73728];   // 3 bufs x [K 8KB | V 8KB | PE 8KB]

    const int bid = blockIdx.x;
    const int sw  = (bid & 7) * 64 + (bid >> 3);   // XCD swizzle (bijective, 512 = 8*64)
    const int qt  = sw & 31, h = sw >> 5;
    const int t   = threadIdx.x;
    const int w   = t >> 6, l = t & 63;
    const int qs  = w & 1, b = w >> 1;
    const int q0  = qt * 64 + qs * 32;
    const int lq  = l & 31;
    const int lh  = l >> 5;

    const int pb = (lq >> 2) & 3;
    const int prow = lq + (pb == 1 ? 4 : (pb == 2 ? -4 : 0));

    bf16x8 Qf[4];
    #pragma unroll
    for (int dm = 0; dm < 4; ++dm)
        Qf[dm] = *(const bf16x8*)(Qb + ((size_t)(b * H_ + h) * L_ + q0 + lq) * HD_ + dm * 16 + lh * 8);

    const bf16*  kb    = Kb  + (size_t)(b * H_ + h) * L_ * HD_;
    const bf16*  vbase = VTb + (size_t)h * HD_ * L_;
    const float* peq   = PE  + ((size_t)h * L_ + q0) * L_;

    const int k_srcoff  = (l >> 3) * HD_ + (((l & 7) ^ (l >> 3)) * 8);
    const int vlb = (l & 7) ^ (l >> 3);
    const size_t v_lane = (size_t)(vlb >> 2) * ((size_t)H_ * HD_ * L_)
                        + (size_t)(l >> 3) * L_ + (vlb & 3) * 8;
    const int pe_srcoff = (l >> 3) * L_ + (((l & 7) ^ (l >> 3)) * 4);

    int kro[4];
    #pragma unroll
    for (int dm = 0; dm < 4; ++dm)
        kro[dm] = prow * 64 + (((dm * 2 + lh) ^ (prow & 7)) * 8);
    int vro[2][2];
    #pragma unroll
    for (int d0 = 0; d0 < 2; ++d0)
        #pragma unroll
        for (int m = 0; m < 2; ++m)
            vro[d0][m] = (d0 * 32 + lq) * 64 + (((b * 4 + m * 2 + lh) ^ (lq & 7)) * 8);
    int peo[4];
    #pragma unroll
    for (int g = 0; g < 4; ++g)
        peo[g] = lq * 32 + ((((g >> 1) * 4 + (g & 1) + lh * 2) ^ (lq & 7)) * 4);

#define SH_K(BUF)  (shm + (BUF) * 24576 + b * 4096)
#define SH_V(BUF)  (shm + (BUF) * 24576 + 8192)
#define SH_PE(BUF) (shm + (BUF) * 24576 + 16384 + qs * 4096)

    f32x16 o[2] = {};
    float mrun = -3e38f, lpart = 0.f;

#define STAGE(BUF, TILE) {                                                              \
    const int kv0_ = (TILE) * 32;                                                       \
    _Pragma("unroll") for (int i = 0; i < 2; ++i) {                                     \
        const int c = 2 * qs + i;                                                       \
        async_ld16(kb + (size_t)(kv0_ + c * 8) * HD_ + k_srcoff, (void*)(SH_K(BUF) + c * 1024)); \
    }                                                                                   \
    _Pragma("unroll") for (int i = 0; i < 2; ++i) {                                     \
        const int cv = 2 * w + i;                                                       \
        async_ld16(vbase + v_lane + (size_t)(cv * 8) * L_ + kv0_, (void*)(SH_V(BUF) + cv * 1024)); \
    }                                                                                   \
    _Pragma("unroll") for (int i = 0; i < 2; ++i) {                                     \
        const int c = 2 * b + i;                                                        \
        async_ld16(peq + (size_t)(c * 8) * L_ + kv0_ + pe_srcoff, (void*)(SH_PE(BUF) + c * 1024)); \
    }                                                                                   \
}

#define COMPUTE(BUF) {                                                                  \
    const bf16*  KL = (const bf16*)SH_K(BUF);                                           \
    const bf16*  VL = (const bf16*)SH_V(BUF);                                           \
    const float* PL = (const float*)SH_PE(BUF);                                         \
    bf16x8 kf0_ = *(const bf16x8*)(KL + kro[0]);                                        \
    bf16x8 kf1_ = *(const bf16x8*)(KL + kro[1]);                                        \
    bf16x8 kf2_ = *(const bf16x8*)(KL + kro[2]);                                        \
    bf16x8 kf3_ = *(const bf16x8*)(KL + kro[3]);                                        \
    f32x16 s = {};                                                                      \
    s = mfma32(kf0_, Qf[0], s);                                                         \
    s = mfma32(kf1_, Qf[1], s);                                                         \
    s = mfma32(kf2_, Qf[2], s);                                                         \
    s = mfma32(kf3_, Qf[3], s);                                                         \
    float4 pef_[4];                                                                     \
    _Pragma("unroll") for (int g = 0; g < 4; ++g)                                       \
        pef_[g] = *(const float4*)(PL + peo[g]);                                        \
    float v_[16];                                                                       \
    _Pragma("unroll") for (int r = 0; r < 16; ++r)                                      \
        v_[r] = fmaf(pef_[r >> 2][r & 3], L2E, s[r]);                                   \
    float t0_ = fmaxf(fmaxf(v_[0], v_[1]), fmaxf(v_[2], v_[3]));                        \
    float t1_ = fmaxf(fmaxf(v_[4], v_[5]), fmaxf(v_[6], v_[7]));                        \
    float t2_ = fmaxf(fmaxf(v_[8], v_[9]), fmaxf(v_[10], v_[11]));                      \
    float t3_ = fmaxf(fmaxf(v_[12], v_[13]), fmaxf(v_[14], v_[15]));                    \
    float vmh_ = fmaxf(fmaxf(t0_, t1_), fmaxf(t2_, t3_));                               \
    float vm_ = fmaxf(vmh_, __shfl_xor(vmh_, 32, 64));                                  \
    float mold_ = mrun;                                                                 \
    float mnew_ = mold_;                                                                \
    if (!__all(vm_ <= mold_ + 10.f)) {                                                  \
        mnew_ = fmaxf(mold_, vm_);                                                      \
        float scl_ = __builtin_amdgcn_exp2f(mold_ - mnew_);                             \
        mrun = mnew_;                                                                   \
        lpart *= scl_;                                                                  \
        _Pragma("unroll") for (int r = 0; r < 16; ++r) { o[0][r] *= scl_; o[1][r] *= scl_; } \
    }                                                                                   \
    float p_[16], ssum_ = 0.f;                                                          \
    _Pragma("unroll") for (int r = 0; r < 16; ++r) {                                    \
        p_[r] = __builtin_amdgcn_exp2f(v_[r] - mnew_);                                  \
        ssum_ += p_[r];                                                                 \
    }                                                                                   \
    lpart += ssum_;                                                                     \
    unsigned a_[8];                                                                     \
    _Pragma("unroll") for (int j = 0; j < 8; ++j)                                       \
        a_[j] = pk2(p_[2 * j], p_[2 * j + 1]);                                          \
    u32x4 w0v_ = { a_[0], a_[1], a_[2], a_[3] };                                        \
    u32x4 w1v_ = { a_[4], a_[5], a_[6], a_[7] };                                        \
    bf16x8 pf0_ = __builtin_bit_cast(bf16x8, w0v_);                                     \
    bf16x8 pf1_ = __builtin_bit_cast(bf16x8, w1v_);                                     \
    o[0] = mfma32(*(const bf16x8*)(VL + vro[0][0]), pf0_, o[0]);                        \
    o[0] = mfma32(*(const bf16x8*)(VL + vro[0][1]), pf1_, o[0]);                        \
    o[1] = mfma32(*(const bf16x8*)(VL + vro[1][0]), pf0_, o[1]);                        \
    o[1] = mfma32(*(const bf16x8*)(VL + vro[1][1]), pf1_, o[1]);                        \
}

// two tiles per barrier-pair; BA/BB = bufs of tiles T0,T0+1; stages T0+3,T0+4 (clamped)
#define STEP2(BA, BB, T0) {                                                             \
    const int s0_ = ((T0) + 3 < 64) ? (T0) + 3 : 63;                                    \
    const int s1_ = ((T0) + 4 < 64) ? (T0) + 4 : 63;                                    \
    asm volatile("s_waitcnt vmcnt(6)" ::: "memory");                                    \
    __builtin_amdgcn_s_barrier();                                                       \
    COMPUTE(BA)                                                                         \
    COMPUTE(BB)                                                                         \
    __builtin_amdgcn_s_barrier();                                                       \
    STAGE(BA, s0_)                                                                      \
    STAGE(BB, s1_)                                                                      \
}

    STAGE(0, 0)
    STAGE(1, 1)
    STAGE(2, 2)

    // iters i=0..29 (tiles 0..59) in 10 groups of 3; buf pattern period-3 in i
    for (int g = 0; g < 10; ++g) {
        const int e = 6 * g;
        STEP2(0, 1, e)        // tiles e,   e+1  (bufs 0,1); stage e+3 -> b0, e+4 -> b1
        STEP2(2, 0, e + 2)    // tiles e+2, e+3  (bufs 2,0); stage e+5 -> b2, e+6 -> b0
        STEP2(1, 2, e + 4)    // tiles e+4, e+5  (bufs 1,2); stage e+7 -> b1, e+8 -> b2
    }
    STEP2(0, 1, 60)           // tiles 60,61; stages t63 -> b0 (real), dummy -> b1
    // tail: tiles 62 (buf 2), 63 (buf 0)
    asm volatile("s_waitcnt vmcnt(6)" ::: "memory");
    __builtin_amdgcn_s_barrier();
    COMPUTE(2)
    COMPUTE(0)
#undef STEP2
#undef COMPUTE
#undef STAGE
#undef SH_K
#undef SH_V
#undef SH_PE

    // drain dangling dummy DMAs before block retirement
    asm volatile("s_waitcnt vmcnt(0)" ::: "memory");

    float lsum = lpart + __shfl_xor(lpart, 32, 64);
    float inv = __builtin_amdgcn_rcpf(lsum);
    #pragma unroll
    for (int d0 = 0; d0 < 2; ++d0)
        #pragma unroll
        for (int r = 0; r < 16; r += 2) {
            float e0 = o[d0][r] * inv;
            float e1 = o[d0][r + 1] * inv;
            int d = d0 * 32 + ((r & 3) + 8 * (r >> 2)) + lh * 4;
            *(unsigned*)(Ob + ((size_t)b * L_ + q0 + lq) * D_ + h * HD_ + d) = pk2(e0, e1);
        }
}

// ---------------------------------------------------------------- launch
extern "C" void kernel_launch(void* const* d_in, const int* in_sizes, int n_in,
                              void* d_out, int out_size, void* d_ws, size_t ws_size,
                              hipStream_t stream) {
    const float* x  = (const float*)d_in[0];
    const float* pe = (const float*)d_in[1];
    const float* Wq = (const float*)d_in[2];
    const float* Wk = (const float*)d_in[3];
    const float* Wv = (const float*)d_in[4];
    const float* Wo = (const float*)d_in[5];
    float* out = (float*)d_out;

    const size_t MD = (size_t)4096 * 1024;

    bf16* Xb  = (bf16*)d_ws;        // x in bf16            [4096][1024]
    bf16* WT  = Xb + MD;            // WqT|WkT|WvT|WoT      [4096][1024]
    bf16* Qb  = WT + MD;            // [bh][L][64]  (pre-scaled by 0.125*log2e)
    bf16* Kb  = Qb + HSZ;
    bf16* Vb  = Kb + HSZ;           // (unused slot; V goes straight to VTb)
    bf16* VTb = Vb + HSZ;           // [bh][64][L]  (written by k_gemm<0> transposed)
    bf16* Ob  = VTb + HSZ;          // attention out        [4096][1024]

    k_prep<<<3072, 256, 0, stream>>>(x, Wq, Wk, Wv, Wo, Xb, WT);
    k_gemm<0, 128><<<dim3(24, 32), 256, 0, stream>>>(Xb, WT, (void*)Qb);     // QKV (V -> VTb)
    k_attn<<<512, 256, 0, stream>>>(Qb, Kb, VTb, pe, Ob);
    k_gemm<1, 64><<<dim3(8, 64), 256, 0, stream>>>(Ob, WT + (size_t)3072 * 1024, (void*)out);
}